// Round 1
// baseline (454.359 us; speedup 1.0000x reference)
//
#include <hip/hip_runtime.h>
#include <hip/hip_bf16.h>

#define E_ 4
#define M_ 4096
#define D_ 1024
#define NIT 4
#define THRESH_ 0.01f

typedef __attribute__((ext_vector_type(8))) short bf16x8;
typedef __attribute__((ext_vector_type(4))) float f32x4;

__device__ inline unsigned short f2bf(float x) {
    unsigned u = __float_as_uint(x);
    unsigned r = (u + 0x7FFFu + ((u >> 16) & 1u)) >> 16;  // RNE
    return (unsigned short)r;
}

__device__ inline float Kf(float s) {            // K = exp(10*(sim-1))
    return __expf(fmaf(10.f, s, -10.f));
}

__device__ inline void unpack8(const int4& raw, float* s) {
    const unsigned* pu = reinterpret_cast<const unsigned*>(&raw);
#pragma unroll
    for (int j = 0; j < 4; ++j) {
        s[2*j]   = __uint_as_float(pu[j] << 16);
        s[2*j+1] = __uint_as_float(pu[j] & 0xFFFF0000u);
    }
}

// ---------------- normalize rows + convert to bf16 ----------------
__global__ __launch_bounds__(256)
void normalize_bf16(const float* __restrict__ g, const float* __restrict__ f,
                    __hip_bfloat16* __restrict__ Sb, __hip_bfloat16* __restrict__ Tb)
{
    const int w = threadIdx.x >> 6, l = threadIdx.x & 63;
    const size_t row = (size_t)blockIdx.x * 4 + w;       // 0..E*M-1
    const float* src = (blockIdx.y == 0 ? g : f) + row * (size_t)D_;
    __hip_bfloat16* dst = (blockIdx.y == 0 ? Sb : Tb) + row * (size_t)D_;
    float4 v[4];
    float ss = 0.f;
#pragma unroll
    for (int i = 0; i < 4; ++i) {
        v[i] = *(const float4*)(src + (i*64 + l) * 4);
        ss += v[i].x*v[i].x + v[i].y*v[i].y + v[i].z*v[i].z + v[i].w*v[i].w;
    }
#pragma unroll
    for (int off = 32; off; off >>= 1) ss += __shfl_xor(ss, off);
    const float inv = 1.f / fmaxf(sqrtf(ss), 1e-12f);
#pragma unroll
    for (int i = 0; i < 4; ++i) {
        ushort4 o;
        o.x = f2bf(v[i].x * inv); o.y = f2bf(v[i].y * inv);
        o.z = f2bf(v[i].z * inv); o.w = f2bf(v[i].w * inv);
        *(ushort4*)((unsigned short*)dst + (i*64 + l) * 4) = o;
    }
}

// ---------------- bf16 NT-GEMM: sim = S @ T^T (m97-style 128^2 tile) ----------------
__global__ __launch_bounds__(256)
void gemm_bt(const __hip_bfloat16* __restrict__ Sb, const __hip_bfloat16* __restrict__ Tb,
             __hip_bfloat16* __restrict__ sim)
{
    const int e = blockIdx.z;
    const int brow = blockIdx.y, bcol = blockIdx.x;
    const int t = threadIdx.x, w = t >> 6, l = t & 63;
    const int wr = w >> 1, wc = w & 1;

    __shared__ __hip_bfloat16 Asl[128*32];
    __shared__ __hip_bfloat16 Bsl[128*32];

    const __hip_bfloat16* Ag = Sb + ((size_t)e*M_ + (size_t)brow*128) * D_;
    const __hip_bfloat16* Bg = Tb + ((size_t)e*M_ + (size_t)bcol*128) * D_;

    f32x4 acc[4][4] = {};

    for (int k0 = 0; k0 < D_; k0 += 32) {
#pragma unroll
        for (int i = 0; i < 2; ++i) {
            const int ci = i*256 + t;                 // 16B chunk id 0..511
            const int row = ci >> 2, c16 = ci & 3;
            const size_t goff = (size_t)row * D_ + k0 + c16*8;
            __builtin_amdgcn_global_load_lds(
                (const __attribute__((address_space(1))) void*)(Ag + goff),
                (__attribute__((address_space(3))) void*)(Asl + ci*8), 16, 0, 0);
            __builtin_amdgcn_global_load_lds(
                (const __attribute__((address_space(1))) void*)(Bg + goff),
                (__attribute__((address_space(3))) void*)(Bsl + ci*8), 16, 0, 0);
        }
        __syncthreads();
        bf16x8 af[4], bfr[4];
#pragma unroll
        for (int m = 0; m < 4; ++m)
            af[m] = *(const bf16x8*)(Asl + (wr*64 + m*16 + (l & 15)) * 32 + (l >> 4) * 8);
#pragma unroll
        for (int n = 0; n < 4; ++n)
            bfr[n] = *(const bf16x8*)(Bsl + (wc*64 + n*16 + (l & 15)) * 32 + (l >> 4) * 8);
#pragma unroll
        for (int m = 0; m < 4; ++m)
#pragma unroll
            for (int n = 0; n < 4; ++n)
                acc[m][n] = __builtin_amdgcn_mfma_f32_16x16x32_bf16(af[m], bfr[n], acc[m][n], 0, 0, 0);
        __syncthreads();
    }

    // C/D layout: col = lane&15, row = (lane>>4)*4 + reg
    unsigned short* Cg = (unsigned short*)(sim + (size_t)e*M_*M_);
    const size_t crow0 = (size_t)brow*128 + wr*64;
    const int ccol0 = bcol*128 + wc*64;
#pragma unroll
    for (int m = 0; m < 4; ++m)
#pragma unroll
        for (int n = 0; n < 4; ++n)
#pragma unroll
            for (int j = 0; j < 4; ++j) {
                const size_t r = crow0 + m*16 + (l >> 4)*4 + j;
                const int c = ccol0 + n*16 + (l & 15);
                Cg[r * M_ + c] = f2bf(acc[m][n][j]);
            }
}

// ---------------- Kc[m] = sum_n K(sim[m,n]) * c[n]   (wave per row) ----------------
__global__ __launch_bounds__(256)
void kc_rowmv(const __hip_bfloat16* __restrict__ sim, const float* __restrict__ c_cur,
              float* __restrict__ Kc, const int* __restrict__ run, int it)
{
    const int e = blockIdx.y;
    if (!run[it*E_ + e]) return;
    const int w = threadIdx.x >> 6, l = threadIdx.x & 63;
    const int row = blockIdx.x * 4 + w;
    const unsigned short* rp = (const unsigned short*)sim + ((size_t)e*M_ + row) * M_;
    const float* cp = c_cur + e*M_;
    float p = 0.f;
#pragma unroll
    for (int i = 0; i < 8; ++i) {
        const int col = (i*64 + l) * 8;
        int4 raw = *(const int4*)(rp + col);
        float4 ca = *(const float4*)(cp + col);
        float4 cb = *(const float4*)(cp + col + 4);
        float s[8]; unpack8(raw, s);
        p += Kf(s[0])*ca.x + Kf(s[1])*ca.y + Kf(s[2])*ca.z + Kf(s[3])*ca.w
           + Kf(s[4])*cb.x + Kf(s[5])*cb.y + Kf(s[6])*cb.z + Kf(s[7])*cb.w;
    }
#pragma unroll
    for (int off = 32; off; off >>= 1) p += __shfl_down(p, off);
    if (l == 0) Kc[e*M_ + row] = p;
}

// ---------------- r = u / Kc; err += |r_new - r_old| ----------------
__global__ __launch_bounds__(256)
void r_update(const float* __restrict__ Kc, float* __restrict__ r_cur,
              float* __restrict__ err, const int* __restrict__ run, int it)
{
    const int e = blockIdx.y;
    if (!run[it*E_ + e]) return;
    const int i = blockIdx.x * 256 + threadIdx.x;
    const float newr = (1.0f / M_) / Kc[e*M_ + i];
    const float oldr = r_cur[e*M_ + i];
    r_cur[e*M_ + i] = newr;
    float d = fabsf(newr - oldr);
#pragma unroll
    for (int off = 32; off; off >>= 1) d += __shfl_down(d, off);
    __shared__ float bl[4];
    if ((threadIdx.x & 63) == 0) bl[threadIdx.x >> 6] = d;
    __syncthreads();
    if (threadIdx.x == 0) atomicAdd(&err[it*E_ + e], bl[0]+bl[1]+bl[2]+bl[3]);
}

// ---------------- partial[mc][n] = sum_{m in chunk} K(sim[m,n]) * r[m] ----------------
__global__ __launch_bounds__(256)
void kt_colmv(const __hip_bfloat16* __restrict__ sim, const float* __restrict__ r_cur,
              float* __restrict__ part, const int* __restrict__ run, int it)
{
    const int e = blockIdx.z;
    if (!run[it*E_ + e]) return;
    const int mc = blockIdx.y;
    const int n0 = blockIdx.x * 2048 + threadIdx.x * 8;
    __shared__ float rsh[128];
    if (threadIdx.x < 128) rsh[threadIdx.x] = r_cur[e*M_ + mc*128 + threadIdx.x];
    __syncthreads();
    const unsigned short* base = (const unsigned short*)sim + ((size_t)e*M_ + (size_t)mc*128) * M_ + n0;
    float acc[8] = {0.f,0.f,0.f,0.f,0.f,0.f,0.f,0.f};
#pragma unroll 4
    for (int m = 0; m < 128; ++m) {
        const float rm = rsh[m];
        int4 raw = *(const int4*)(base + (size_t)m * M_);
        float s[8]; unpack8(raw, s);
#pragma unroll
        for (int j = 0; j < 8; ++j) acc[j] = fmaf(rm, Kf(s[j]), acc[j]);
    }
    float* pp = part + (size_t)(e*32 + mc) * M_ + n0;
    float4 o0 = {acc[0], acc[1], acc[2], acc[3]};
    float4 o1 = {acc[4], acc[5], acc[6], acc[7]};
    *(float4*)pp = o0;
    *(float4*)(pp + 4) = o1;
}

// ---------------- c = v / sum_mc partial[mc][n] ----------------
__global__ __launch_bounds__(256)
void c_update(const float* __restrict__ part, float* __restrict__ c_cur,
              const int* __restrict__ run, int it)
{
    const int e = blockIdx.y;
    if (!run[it*E_ + e]) return;
    const int n = blockIdx.x * 256 + threadIdx.x;
    float s = 0.f;
#pragma unroll
    for (int mc = 0; mc < 32; ++mc) s += part[(size_t)(e*32 + mc) * M_ + n];
    c_cur[e*M_ + n] = (1.0f / M_) / s;
}

// ---------------- convergence: run[it+1] = run[it] && (mean_err >= THRESH) ----------------
__global__ void flag_update(const float* __restrict__ err, int* __restrict__ run, int it)
{
    const int e = threadIdx.x;
    if (e < E_) {
        const int cont = run[it*E_ + e] && (err[it*E_ + e] * (1.0f / M_) >= THRESH_);
        run[(it+1)*E_ + e] = cont;
    }
}

// ---------------- loss_e = sum_{m,n} r[m] c[n] K(sim) sim ----------------
__global__ __launch_bounds__(256)
void loss_kernel(const __hip_bfloat16* __restrict__ sim, const float* __restrict__ r_cur,
                 const float* __restrict__ c_cur, float* __restrict__ loss_acc)
{
    const int e = blockIdx.z;
    const int mc = blockIdx.y;
    const int n0 = blockIdx.x * 2048 + threadIdx.x * 8;
    __shared__ float rsh[128];
    if (threadIdx.x < 128) rsh[threadIdx.x] = r_cur[e*M_ + mc*128 + threadIdx.x];
    __syncthreads();
    float c8[8];
    {
        float4 ca = *(const float4*)(c_cur + e*M_ + n0);
        float4 cb = *(const float4*)(c_cur + e*M_ + n0 + 4);
        c8[0]=ca.x; c8[1]=ca.y; c8[2]=ca.z; c8[3]=ca.w;
        c8[4]=cb.x; c8[5]=cb.y; c8[6]=cb.z; c8[7]=cb.w;
    }
    const unsigned short* base = (const unsigned short*)sim + ((size_t)e*M_ + (size_t)mc*128) * M_ + n0;
    float p = 0.f;
#pragma unroll 4
    for (int m = 0; m < 128; ++m) {
        const float rm = rsh[m];
        int4 raw = *(const int4*)(base + (size_t)m * M_);
        float s[8]; unpack8(raw, s);
        float q = 0.f;
#pragma unroll
        for (int j = 0; j < 8; ++j) q = fmaf(c8[j] * Kf(s[j]), s[j], q);
        p = fmaf(rm, q, p);
    }
#pragma unroll
    for (int off = 32; off; off >>= 1) p += __shfl_down(p, off);
    __shared__ float bl[4];
    if ((threadIdx.x & 63) == 0) bl[threadIdx.x >> 6] = p;
    __syncthreads();
    if (threadIdx.x == 0) atomicAdd(&loss_acc[e], bl[0]+bl[1]+bl[2]+bl[3]);
}

// ---------------- init + final weighting ----------------
__global__ void init_rc(float* __restrict__ r_cur, float* __restrict__ c_cur, int* __restrict__ run)
{
    const int i = blockIdx.x * 256 + threadIdx.x;
    if (i < E_*M_) { r_cur[i] = 1.f; c_cur[i] = 1.f; }
    if (i < E_) run[i] = 1;
}

__global__ void finalize(const float* __restrict__ loss_acc, const float* __restrict__ prev,
                         float* __restrict__ out)
{
    if (threadIdx.x == 0 && blockIdx.x == 0) {
        float l[E_], wgt[E_], sw = 0.f, tot = 0.f;
        for (int e = 0; e < E_; ++e) {
            l[e] = loss_acc[e];
            wgt[e] = expf(l[e] / (prev[e] + 1e-8f));
            sw += wgt[e];
        }
        for (int e = 0; e < E_; ++e) tot += (wgt[e] / sw * (float)E_) * l[e];
        out[0] = tot;
    }
}

extern "C" void kernel_launch(void* const* d_in, const int* in_sizes, int n_in,
                              void* d_out, int out_size, void* d_ws, size_t ws_size,
                              hipStream_t stream)
{
    (void)in_sizes; (void)n_in; (void)out_size; (void)ws_size;
    const float* gts   = (const float*)d_in[0];
    const float* feats = (const float*)d_in[1];
    const float* prev  = (const float*)d_in[2];
    float* out = (float*)d_out;
    char* ws = (char*)d_ws;

    __hip_bfloat16* sim = (__hip_bfloat16*)ws;                       // 134,217,728 B
    __hip_bfloat16* Sb  = (__hip_bfloat16*)(ws + 134217728);         //  33,554,432 B
    __hip_bfloat16* Tb  = (__hip_bfloat16*)(ws + 167772160);         //  33,554,432 B
    float* part     = (float*)(ws + 201326592);                      //   2,097,152 B
    float* Kc       = (float*)(ws + 203423744);                      //      65,536 B
    float* r_cur    = (float*)(ws + 203489280);                      //      65,536 B
    float* c_cur    = (float*)(ws + 203554816);                      //      65,536 B
    float* err      = (float*)(ws + 203620352);                      //          64 B
    int*   run      = (int*)  (ws + 203620416);                      //          80 B
    float* loss_acc = (float*)(ws + 203620496);                      //          16 B

    hipMemsetAsync(err, 0, 160, stream);   // err + run + loss_acc
    init_rc<<<dim3(64), 256, 0, stream>>>(r_cur, c_cur, run);
    normalize_bf16<<<dim3(E_*M_/4, 2), 256, 0, stream>>>(gts, feats, Sb, Tb);
    gemm_bt<<<dim3(32, 32, E_), 256, 0, stream>>>(Sb, Tb, sim);
    for (int it = 0; it < NIT; ++it) {
        kc_rowmv<<<dim3(M_/4, E_), 256, 0, stream>>>(sim, c_cur, Kc, run, it);
        r_update<<<dim3(M_/256, E_), 256, 0, stream>>>(Kc, r_cur, err, run, it);
        kt_colmv<<<dim3(2, 32, E_), 256, 0, stream>>>(sim, r_cur, part, run, it);
        c_update<<<dim3(M_/256, E_), 256, 0, stream>>>(part, c_cur, run, it);
        flag_update<<<1, 64, 0, stream>>>(err, run, it);
    }
    loss_kernel<<<dim3(2, 32, E_), 256, 0, stream>>>(sim, r_cur, c_cur, loss_acc);
    finalize<<<1, 64, 0, stream>>>(loss_acc, prev, out);
}